// Round 8
// baseline (259.358 us; speedup 1.0000x reference)
//
#include <hip/hip_runtime.h>
#include <hip/hip_bf16.h>

// Problem constants (match reference)
#define N_NODES 50000
#define N_EDGES 800000
#define HID 128          // HEADS*HEAD_DIM
#define NEG_SLOPE 0.2f
#define BN_EPS 1e-5f

// CSR binning parameters
#define NBLK 256         // blocks over edges
#define BINSZ 512        // nodes per bin (power of 2)
#define BINSH 9
#define NBINS 98         // ceil(N_NODES / BINSZ)

typedef __bf16 v8bf __attribute__((ext_vector_type(8)));
typedef float v4f __attribute__((ext_vector_type(4)));

__device__ __forceinline__ float leaky(float v) {
    return (v > 0.f) ? v : v * NEG_SLOPE;
}
__device__ __forceinline__ unsigned int f2bu(float f) {
    __hip_bfloat16 b = __float2bfloat16(f);
    return (unsigned int)*reinterpret_cast<unsigned short*>(&b);
}
__device__ __forceinline__ unsigned int pack2bf(float lo, float hi) {
    return f2bu(lo) | (f2bu(hi) << 16);
}

// ---------------------------------------------------------------------------
// K_prepw: convert the 3 weight matrices to bf16 once (L2-resident afterwards)
// grid: 48 x 256
// ---------------------------------------------------------------------------
__global__ __launch_bounds__(256) void k_prepw(const float* __restrict__ w0,
                                               const float* __restrict__ w1,
                                               const float* __restrict__ wsk,
                                               unsigned short* __restrict__ wb) {
    const int WQ = 128 * 128 / 4;         // 4096 quads per matrix
    int q = blockIdx.x * 256 + threadIdx.x;
    if (q >= 3 * WQ) return;
    int mat = q >> 12;
    int rem = q & 4095;
    const float* W = (mat == 0) ? w0 : (mat == 1) ? w1 : wsk;
    float4 v = ((const float4*)W)[rem];
    ushort4 o;
    o.x = (unsigned short)f2bu(v.x);
    o.y = (unsigned short)f2bu(v.y);
    o.z = (unsigned short)f2bu(v.z);
    o.w = (unsigned short)f2bu(v.w);
    *(ushort4*)(wb + (size_t)mat * 16384 + rem * 4) = o;
}

// ---------------------------------------------------------------------------
// CSR pass A: per-block LDS histogram of dst bins. grid: (NBLK, 2)
// ---------------------------------------------------------------------------
__global__ __launch_bounds__(256) void k_bincount(const int* __restrict__ dst0,
                                                  const int* __restrict__ dst1,
                                                  int* __restrict__ bincnt) {
    int rel = blockIdx.y;
    const int* dst = rel ? dst1 : dst0;
    __shared__ int cnt[NBINS];
    for (int i = threadIdx.x; i < NBINS; i += 256) cnt[i] = 0;
    __syncthreads();
    const int CH = (N_EDGES + NBLK - 1) / NBLK;   // 3125
    int b0 = blockIdx.x * CH;
    int b1 = min(N_EDGES, b0 + CH);
    for (int e = b0 + threadIdx.x; e < b1; e += 256)
        atomicAdd(&cnt[dst[e] >> BINSH], 1);
    __syncthreads();
    for (int i = threadIdx.x; i < NBINS; i += 256)
        bincnt[rel * NBINS * NBLK + i * NBLK + blockIdx.x] = cnt[i];
}

// ---------------------------------------------------------------------------
// CSR pass B: in-place exclusive scan of bincnt per relation. grid: (2)
// ---------------------------------------------------------------------------
__global__ __launch_bounds__(1024) void k_binscan(int* __restrict__ bincnt) {
    int* a = bincnt + blockIdx.x * NBINS * NBLK;
    const int TOT = NBINS * NBLK;                 // 25088
    const int CH = (TOT + 1023) / 1024;           // 25
    int tid = threadIdx.x;
    int base = tid * CH;
    int lv[CH];
    int sum = 0;
    for (int i = 0; i < CH; i++) {
        int idx = base + i;
        int v = (idx < TOT) ? a[idx] : 0;
        lv[i] = sum;
        sum += v;
    }
    __shared__ int ls[1024];
    ls[tid] = sum;
    __syncthreads();
    for (int ofs = 1; ofs < 1024; ofs <<= 1) {
        int v = (tid >= ofs) ? ls[tid - ofs] : 0;
        __syncthreads();
        ls[tid] += v;
        __syncthreads();
    }
    int pre = tid ? ls[tid - 1] : 0;
    for (int i = 0; i < CH; i++) {
        int idx = base + i;
        if (idx < TOT) a[idx] = pre + lv[i];
    }
}

// ---------------------------------------------------------------------------
// CSR pass C: scatter packed (dst_local|src<<9, ew) 8B pairs into
// per-(bin,block) contiguous runs. grid: (NBLK, 2)
// ---------------------------------------------------------------------------
__global__ __launch_bounds__(256) void k_binscatter(const int* __restrict__ dst0,
                                                    const int* __restrict__ dst1,
                                                    const int* __restrict__ src0,
                                                    const int* __restrict__ src1,
                                                    const float* __restrict__ ew0,
                                                    const float* __restrict__ ew1,
                                                    const int* __restrict__ bincnt,
                                                    int2* __restrict__ pairs0,
                                                    int2* __restrict__ pairs1) {
    int rel = blockIdx.y;
    const int* dst = rel ? dst1 : dst0;
    const int* src = rel ? src1 : src0;
    const float* ew = rel ? ew1 : ew0;
    int2* pairs = rel ? pairs1 : pairs0;
    __shared__ int cur[NBINS];
    for (int i = threadIdx.x; i < NBINS; i += 256)
        cur[i] = bincnt[rel * NBINS * NBLK + i * NBLK + blockIdx.x];
    __syncthreads();
    const int CH = (N_EDGES + NBLK - 1) / NBLK;
    int b0 = blockIdx.x * CH;
    int b1 = min(N_EDGES, b0 + CH);
    for (int e = b0 + threadIdx.x; e < b1; e += 256) {
        int d = dst[e];
        int pos = atomicAdd(&cur[d >> BINSH], 1);
        unsigned int packed = (unsigned int)(d & (BINSZ - 1)) |
                              ((unsigned int)src[e] << BINSH);
        pairs[pos] = make_int2((int)packed, __float_as_int(ew[e]));
    }
}

// ---------------------------------------------------------------------------
// CSR pass D: per (rel,bin): LDS histogram -> scan -> offs (+sentinel) ->
// place 16B edge records (src, ew, el0, el1) sorted by dst. grid: (NBINS, 2)
// ---------------------------------------------------------------------------
__global__ __launch_bounds__(256) void k_csr(const int* __restrict__ bincnt,
                                             const int2* __restrict__ pairs0,
                                             const int2* __restrict__ pairs1,
                                             const float* __restrict__ el0,
                                             const float* __restrict__ el1,
                                             int* __restrict__ offs0,
                                             int* __restrict__ offs1,
                                             int4* __restrict__ rec0,
                                             int4* __restrict__ rec1) {
    int rel = blockIdx.y;
    const int2* pairs = rel ? pairs1 : pairs0;
    const float* el = rel ? el1 : el0;
    int* offs = rel ? offs1 : offs0;
    int4* rec = rel ? rec1 : rec0;
    int bin = blockIdx.x;
    int tid = threadIdx.x;
    const int* bc = bincnt + rel * NBINS * NBLK;
    int pbase = bc[bin * NBLK];
    int pend = (bin < NBINS - 1) ? bc[(bin + 1) * NBLK] : N_EDGES;
    int n0 = bin << BINSH;
    int nn = min(N_NODES - n0, BINSZ);

    __shared__ int s_deg[BINSZ];
    __shared__ int s_ts[256];
    for (int i = tid; i < BINSZ; i += 256) s_deg[i] = 0;
    __syncthreads();
    for (int p = pbase + tid; p < pend; p += 256)
        atomicAdd(&s_deg[((unsigned int)pairs[p].x) & (BINSZ - 1)], 1);
    __syncthreads();

    int d0 = s_deg[tid * 2], d1 = s_deg[tid * 2 + 1];
    s_ts[tid] = d0 + d1;
    __syncthreads();
    for (int ofs = 1; ofs < 256; ofs <<= 1) {
        int v = (tid >= ofs) ? s_ts[tid - ofs] : 0;
        __syncthreads();
        s_ts[tid] += v;
        __syncthreads();
    }
    int pre = tid ? s_ts[tid - 1] : 0;
    s_deg[tid * 2] = pbase + pre;
    s_deg[tid * 2 + 1] = pbase + pre + d0;
    __syncthreads();

    for (int l = tid; l < nn; l += 256) offs[n0 + l] = s_deg[l];
    if (bin == NBINS - 1 && tid == 0) offs[N_NODES] = N_EDGES;
    __syncthreads();

    for (int p = pbase + tid; p < pend; p += 256) {
        int2 pr = pairs[p];
        unsigned int u = (unsigned int)pr.x;
        int dl = (int)(u & (BINSZ - 1));
        int s = (int)(u >> BINSH);
        int pos = atomicAdd(&s_deg[dl], 1);
        float2 ev = *(const float2*)(el + 2 * s);
        rec[pos] = make_int4(s, pr.y,
                             __float_as_int(ev.x), __float_as_int(ev.y));
    }
}

// ---------------------------------------------------------------------------
// K1: MFMA GEMM. Block = 64 rows x all 6 (mat,half) slices.
// A staged once in LDS (f32->bf16 inline, XOR-swizzled) then register-resident;
// B read directly from bf16 global (L2-hot; no LDS, no per-slice barriers).
// grid (782). Block = 4 waves; wave = 16 rows x 64 cols per slice.
// ---------------------------------------------------------------------------
__global__ __launch_bounds__(256) void k_gemm_mfma(
    const float* __restrict__ x, const unsigned short* __restrict__ wb,
    const float* __restrict__ skip_b,
    const float* __restrict__ al0, const float* __restrict__ ar0,
    const float* __restrict__ al1, const float* __restrict__ ar1,
    unsigned short* __restrict__ fb0, unsigned short* __restrict__ fb1,
    float* __restrict__ el0, float* __restrict__ er0,
    float* __restrict__ el1, float* __restrict__ er1,
    float* __restrict__ hs) {
    __shared__ unsigned short As[64][128];
    int tid = threadIdx.x;
    int m0 = blockIdx.x * 64;

    // stage A once from f32, convert, XOR-swizzle on 16B granules
#pragma unroll
    for (int i = 0; i < 4; i++) {
        int idx = tid * 4 + i;
        int row = idx >> 4, seg = idx & 15;
        int gr = m0 + row;
        uint4 o = make_uint4(0, 0, 0, 0);
        if (gr < N_NODES) {
            const float* p = x + (size_t)gr * HID + seg * 8;
            float4 p0 = *(const float4*)p;
            float4 p1 = *(const float4*)(p + 4);
            o.x = pack2bf(p0.x, p0.y);
            o.y = pack2bf(p0.z, p0.w);
            o.z = pack2bf(p1.x, p1.y);
            o.w = pack2bf(p1.z, p1.w);
        }
        *(uint4*)(&As[row][(seg ^ (row & 7)) * 8]) = o;
    }
    __syncthreads();

    int w = tid >> 6, l = tid & 63;
    int lr = l & 15, lg = l >> 4;
    int arow = w * 16 + lr;
    v8bf afrag[4];
#pragma unroll
    for (int kb = 0; kb < 4; kb++)
        afrag[kb] = *(v8bf*)(&As[arow][((kb * 4 + lg) ^ (arow & 7)) * 8]);

    for (int s = 0; s < 6; s++) {
        int mat = s >> 1;                 // 0=fc_w0, 1=fc_w1, 2=skip_w
        int j0 = (s & 1) * 64;
        const unsigned short* wmat = wb + (size_t)mat * 16384;

        v4f acc[4] = {};
#pragma unroll
        for (int nt = 0; nt < 4; nt++) {
            const unsigned short* brow = wmat + (size_t)(j0 + nt * 16 + lr) * HID;
#pragma unroll
            for (int kb = 0; kb < 4; kb++) {
                v8bf bfrag = *(const v8bf*)(brow + kb * 32 + lg * 8);
                acc[nt] = __builtin_amdgcn_mfma_f32_16x16x32_bf16(
                    afrag[kb], bfrag, acc[nt], 0, 0, 0);
            }
        }

        // C/D layout: col = lane&15, row = (lane>>4)*4 + r   [m89-verified]
        if (mat < 2) {
            int h = s & 1;
            const float* al = mat ? al1 : al0;
            const float* ar = mat ? ar1 : ar0;
            float* elp = mat ? el1 : el0;
            float* erp = mat ? er1 : er0;
            unsigned short* fbp = mat ? fb1 : fb0;
            float elv[4] = {0.f, 0.f, 0.f, 0.f};
            float erv[4] = {0.f, 0.f, 0.f, 0.f};
#pragma unroll
            for (int nt = 0; nt < 4; nt++) {
                int colg = j0 + nt * 16 + lr;
                float av = al[colg], rv = ar[colg];
#pragma unroll
                for (int r = 0; r < 4; r++) {
                    elv[r] += acc[nt][r] * av;
                    erv[r] += acc[nt][r] * rv;
                }
            }
#pragma unroll
            for (int m = 1; m < 16; m <<= 1)
#pragma unroll
                for (int r = 0; r < 4; r++) {
                    elv[r] += __shfl_xor(elv[r], m);
                    erv[r] += __shfl_xor(erv[r], m);
                }
#pragma unroll
            for (int r = 0; r < 4; r++) {
                int grow = m0 + w * 16 + lg * 4 + r;
                if (grow >= N_NODES) continue;
#pragma unroll
                for (int nt = 0; nt < 4; nt++) {
                    int colg = j0 + nt * 16 + lr;
                    fbp[(size_t)grow * HID + colg] =
                        (unsigned short)f2bu(acc[nt][r]);
                }
                if (lr == 0) {
                    elp[grow * 2 + h] = elv[r];
                    erp[grow * 2 + h] = erv[r];
                }
            }
        } else {
#pragma unroll
            for (int r = 0; r < 4; r++) {
                int grow = m0 + w * 16 + lg * 4 + r;
                if (grow >= N_NODES) continue;
#pragma unroll
                for (int nt = 0; nt < 4; nt++) {
                    int colg = j0 + nt * 16 + lr;
                    hs[(size_t)grow * HID + colg] = acc[nt][r] + skip_b[colg];
                }
            }
        }
    }
}

// ---------------------------------------------------------------------------
// K_aggregate: wave per dst node. Per 64-edge chunk: denominator pass, then
// (src, packed-alpha) published once to a per-wave LDS strip; gather loop
// reads it back via broadcast ds_read_b64 (imm offsets) -> no bpermute, no
// divergent recompute in the inner loop. h updated in place.
// ---------------------------------------------------------------------------
__device__ __forceinline__ void agg_rel3(const int* __restrict__ offs,
                                         const int4* __restrict__ rec,
                                         const float* __restrict__ er,
                                         const unsigned short* __restrict__ fb,
                                         int n, int lane, int cb, int sub,
                                         int hh, float* a,
                                         unsigned long long* __restrict__ sed) {
    int b = offs[n];
    int e_end = offs[n + 1];
    int deg = e_end - b;
    if (deg <= 0) return;
    float ern0 = er[2 * n], ern1 = er[2 * n + 1];

    const int NC = 4;
    int cs[NC];
    float cw0[NC], cw1[NC];
    float d0 = 0.f, d1 = 0.f;
    int nchunk = (deg + 63) >> 6;
    for (int ch = 0; ch < nchunk; ch++) {
        int p = b + (ch << 6) + lane;
        int s = 0;
        float w0 = 0.f, w1 = 0.f;
        if (p < e_end) {
            int4 r = rec[p];
            s = r.x;
            float wgt = __int_as_float(r.y);
            float x0 = expf(leaky(__int_as_float(r.z) + ern0));
            float x1 = expf(leaky(__int_as_float(r.w) + ern1));
            d0 += x0;
            d1 += x1;
            w0 = x0 * wgt;
            w1 = x1 * wgt;
        }
        if (ch < NC) {
            cs[ch] = s;
            cw0[ch] = w0;
            cw1[ch] = w1;
        }
    }
#pragma unroll
    for (int m = 32; m; m >>= 1) {
        d0 += __shfl_xor(d0, m);
        d1 += __shfl_xor(d1, m);
    }
    float inv0 = 1.f / d0, inv1 = 1.f / d1;
    const unsigned short* fbc = fb + cb * 8;

    for (int ch = 0; ch < nchunk; ch++) {
        int s;
        unsigned int pk;
        if (ch < NC) {
            s = cs[ch];
            pk = pack2bf(cw0[ch] * inv0, cw1[ch] * inv1);
        } else {                              // rare: recompute
            int p = b + (ch << 6) + lane;
            s = 0;
            pk = 0;
            if (p < e_end) {
                int4 r = rec[p];
                s = r.x;
                float wgt = __int_as_float(r.y);
                pk = pack2bf(expf(leaky(__int_as_float(r.z) + ern0)) * wgt * inv0,
                             expf(leaky(__int_as_float(r.w) + ern1)) * wgt * inv1);
            }
        }
        // publish this chunk's edge data (wave-lockstep; DS pipe is in-order
        // per wave, so this write cannot pass the previous chunk's reads)
        sed[lane] = ((unsigned long long)pk << 32) | (unsigned int)s;
        asm volatile("s_waitcnt lgkmcnt(0)" ::: "memory");
        int cnt = deg - (ch << 6);
        if (cnt > 64) cnt = 64;
        int ng = (cnt + 3) >> 2;
#pragma unroll 4
        for (int g = 0; g < ng; g++) {
            unsigned long long v = sed[(g << 2) + sub];   // 16-lane broadcast
            int sj = (int)(unsigned int)v;
            unsigned int pkj = (unsigned int)(v >> 32);
            float aj = __uint_as_float(hh ? (pkj & 0xffff0000u) : (pkj << 16));
            uint4 fv = *(const uint4*)(fbc + (size_t)sj * HID);
            a[0] += aj * __uint_as_float(fv.x << 16);
            a[1] += aj * __uint_as_float(fv.x & 0xffff0000u);
            a[2] += aj * __uint_as_float(fv.y << 16);
            a[3] += aj * __uint_as_float(fv.y & 0xffff0000u);
            a[4] += aj * __uint_as_float(fv.z << 16);
            a[5] += aj * __uint_as_float(fv.z & 0xffff0000u);
            a[6] += aj * __uint_as_float(fv.w << 16);
            a[7] += aj * __uint_as_float(fv.w & 0xffff0000u);
        }
    }
}

__global__ __launch_bounds__(256) void k_aggregate(
    const int* __restrict__ offs0, const int4* __restrict__ rec0,
    const float* __restrict__ er0, const unsigned short* __restrict__ fb0,
    const int* __restrict__ offs1, const int4* __restrict__ rec1,
    const float* __restrict__ er1, const unsigned short* __restrict__ fb1,
    const float* __restrict__ bias0, const float* __restrict__ bias1,
    float* __restrict__ h) {
    __shared__ unsigned long long sed[4][64];
    int wave = threadIdx.x >> 6, lane = threadIdx.x & 63;
    int n = blockIdx.x * 4 + wave;
    if (n >= N_NODES) return;
    int cb = lane & 15;        // col block: cols cb*8 .. cb*8+7
    int sub = lane >> 4;       // sub-edge slot
    int hh = cb >> 3;          // head of these cols
    float a[8] = {0.f, 0.f, 0.f, 0.f, 0.f, 0.f, 0.f, 0.f};
    agg_rel3(offs0, rec0, er0, fb0, n, lane, cb, sub, hh, a, &sed[wave][0]);
    agg_rel3(offs1, rec1, er1, fb1, n, lane, cb, sub, hh, a, &sed[wave][0]);
#pragma unroll
    for (int j = 0; j < 8; j++) {
        a[j] += __shfl_xor(a[j], 16);
        a[j] += __shfl_xor(a[j], 32);
    }
    if (sub == 0) {
        size_t base = (size_t)n * HID + cb * 8;
        float4 v0 = *(const float4*)(h + base);
        float4 v1 = *(const float4*)(h + base + 4);
        int c0 = cb * 8;
        float4 o0, o1;
        o0.x = v0.x + fmaxf(a[0] + bias0[c0 + 0] + bias1[c0 + 0], 0.f);
        o0.y = v0.y + fmaxf(a[1] + bias0[c0 + 1] + bias1[c0 + 1], 0.f);
        o0.z = v0.z + fmaxf(a[2] + bias0[c0 + 2] + bias1[c0 + 2], 0.f);
        o0.w = v0.w + fmaxf(a[3] + bias0[c0 + 3] + bias1[c0 + 3], 0.f);
        o1.x = v1.x + fmaxf(a[4] + bias0[c0 + 4] + bias1[c0 + 4], 0.f);
        o1.y = v1.y + fmaxf(a[5] + bias0[c0 + 5] + bias1[c0 + 5], 0.f);
        o1.z = v1.z + fmaxf(a[6] + bias0[c0 + 6] + bias1[c0 + 6], 0.f);
        o1.w = v1.w + fmaxf(a[7] + bias0[c0 + 7] + bias1[c0 + 7], 0.f);
        *(float4*)(h + base) = o0;
        *(float4*)(h + base + 4) = o1;
    }
}

// ---------------------------------------------------------------------------
// K_bnstats: per-column partial sums over h (float4 loads).
// EXACTLY 512 blocks x 256 threads.
// ---------------------------------------------------------------------------
__global__ __launch_bounds__(256) void k_bnstats(const float* __restrict__ h,
                                                 double* __restrict__ psum,
                                                 double* __restrict__ psumsq) {
    int tid = threadIdx.x;
    const float4* h4 = (const float4*)h;
    double s[4] = {0.0, 0.0, 0.0, 0.0};
    double q[4] = {0.0, 0.0, 0.0, 0.0};
    const int totalv = N_NODES * HID / 4;         // 1.6M float4s
    const int stride = 512 * 256;                 // multiple of 32: cols fixed
    for (int i = blockIdx.x * 256 + tid; i < totalv; i += stride) {
        float4 v = h4[i];
        s[0] += v.x; q[0] += (double)v.x * v.x;
        s[1] += v.y; q[1] += (double)v.y * v.y;
        s[2] += v.z; q[2] += (double)v.z * v.z;
        s[3] += v.w; q[3] += (double)v.w * v.w;
    }
    __shared__ double ls[256][4], lq[256][4];
#pragma unroll
    for (int j = 0; j < 4; j++) {
        ls[tid][j] = s[j];
        lq[tid][j] = q[j];
    }
    __syncthreads();
    if (tid < 32) {                                // col quad = tid*4 + j
#pragma unroll
        for (int j = 0; j < 4; j++) {
            double ss = 0.0, qq = 0.0;
            for (int t = tid; t < 256; t += 32) {
                ss += ls[t][j];
                qq += lq[t][j];
            }
            psum[blockIdx.x * 128 + tid * 4 + j] = ss;
            psumsq[blockIdx.x * 128 + tid * 4 + j] = qq;
        }
    }
}

__global__ void k_bn_finalize(const double* __restrict__ psum,
                              const double* __restrict__ psumsq,
                              const float* __restrict__ gamma,
                              const float* __restrict__ beta,
                              float* __restrict__ ss) {
    int c = threadIdx.x;
    double s = 0.0, q = 0.0;
    for (int b = 0; b < 512; b++) {
        s += psum[b * 128 + c];
        q += psumsq[b * 128 + c];
    }
    double mu = s / N_NODES;
    double var = q / N_NODES - mu * mu;
    float sc = gamma[c] * (float)(1.0 / sqrt(var + (double)BN_EPS));
    ss[c] = sc;
    ss[128 + c] = beta[c] - (float)mu * sc;
}

// ---------------------------------------------------------------------------
// K_classify: MFMA 16x16x32. Wave = 16 nodes x 16 classes, K=128.
// A = relu(h*sc+sh) -> bf16; B = clf_w -> bf16. grid 782 x 4 waves.
// ---------------------------------------------------------------------------
__global__ __launch_bounds__(256) void k_classify(const float* __restrict__ h,
                                                  const float* __restrict__ ss,
                                                  const float* __restrict__ clf_w,
                                                  const float* __restrict__ clf_b,
                                                  float* __restrict__ out) {
    int w = threadIdx.x >> 6, l = threadIdx.x & 63;
    int lr = l & 15, lg = l >> 4;
    int n0 = (blockIdx.x * 4 + w) * 16;
    if (n0 >= N_NODES) return;

    v8bf afrag[4], bfrag[4];
#pragma unroll
    for (int kb = 0; kb < 4; kb++) {
        int k0 = kb * 32 + lg * 8;
        const float* bp = clf_w + lr * HID + k0;
        float4 b0 = *(const float4*)bp;
        float4 b1 = *(const float4*)(bp + 4);
        bfrag[kb][0] = (__bf16)b0.x; bfrag[kb][1] = (__bf16)b0.y;
        bfrag[kb][2] = (__bf16)b0.z; bfrag[kb][3] = (__bf16)b0.w;
        bfrag[kb][4] = (__bf16)b1.x; bfrag[kb][5] = (__bf16)b1.y;
        bfrag[kb][6] = (__bf16)b1.z; bfrag[kb][7] = (__bf16)b1.w;
        const float* ap = h + (size_t)(n0 + lr) * HID + k0;
        float4 a0 = *(const float4*)ap;
        float4 a1 = *(const float4*)(ap + 4);
        float4 sc0 = *(const float4*)(ss + k0);
        float4 sc1 = *(const float4*)(ss + k0 + 4);
        float4 sh0 = *(const float4*)(ss + 128 + k0);
        float4 sh1 = *(const float4*)(ss + 128 + k0 + 4);
        afrag[kb][0] = (__bf16)fmaxf(a0.x * sc0.x + sh0.x, 0.f);
        afrag[kb][1] = (__bf16)fmaxf(a0.y * sc0.y + sh0.y, 0.f);
        afrag[kb][2] = (__bf16)fmaxf(a0.z * sc0.z + sh0.z, 0.f);
        afrag[kb][3] = (__bf16)fmaxf(a0.w * sc0.w + sh0.w, 0.f);
        afrag[kb][4] = (__bf16)fmaxf(a1.x * sc1.x + sh1.x, 0.f);
        afrag[kb][5] = (__bf16)fmaxf(a1.y * sc1.y + sh1.y, 0.f);
        afrag[kb][6] = (__bf16)fmaxf(a1.z * sc1.z + sh1.z, 0.f);
        afrag[kb][7] = (__bf16)fmaxf(a1.w * sc1.w + sh1.w, 0.f);
    }
    v4f acc = {};
#pragma unroll
    for (int kb = 0; kb < 4; kb++)
        acc = __builtin_amdgcn_mfma_f32_16x16x32_bf16(afrag[kb], bfrag[kb],
                                                      acc, 0, 0, 0);
    float cb = clf_b[lr];
#pragma unroll
    for (int r = 0; r < 4; r++) {
        int n = n0 + lg * 4 + r;
        out[(size_t)n * 16 + lr] = acc[r] + cb;
    }
}

// ---------------------------------------------------------------------------
extern "C" void kernel_launch(void* const* d_in, const int* in_sizes, int n_in,
                              void* d_out, int out_size, void* d_ws, size_t ws_size,
                              hipStream_t stream) {
    (void)in_sizes; (void)n_in; (void)out_size; (void)ws_size;
    const float* x      = (const float*)d_in[0];
    const int*   src0   = (const int*)d_in[1];
    const int*   dst0   = (const int*)d_in[2];
    const float* ew0    = (const float*)d_in[3];
    const int*   src1   = (const int*)d_in[4];
    const int*   dst1   = (const int*)d_in[5];
    const float* ew1    = (const float*)d_in[6];
    const float* fc_w0  = (const float*)d_in[7];
    const float* bias0  = (const float*)d_in[8];
    const float* al0    = (const float*)d_in[9];
    const float* ar0    = (const float*)d_in[10];
    const float* fc_w1  = (const float*)d_in[11];
    const float* bias1  = (const float*)d_in[12];
    const float* al1    = (const float*)d_in[13];
    const float* ar1    = (const float*)d_in[14];
    const float* skip_w = (const float*)d_in[15];
    const float* skip_b = (const float*)d_in[16];
    const float* gamma  = (const float*)d_in[17];
    const float* beta   = (const float*)d_in[18];
    const float* clf_w  = (const float*)d_in[19];
    const float* clf_b  = (const float*)d_in[20];
    float* out = (float*)d_out;

    char* wsp = (char*)d_ws;
    size_t off = 0;
    auto alloc = [&](size_t bytes) -> char* {
        char* p = wsp + off;
        off += (bytes + 255) & ~(size_t)255;
        return p;
    };
    unsigned short* wbf = (unsigned short*)alloc((size_t)3 * 16384 * 2);
    unsigned short* fb0 = (unsigned short*)alloc((size_t)N_NODES * HID * 2);
    unsigned short* fb1 = (unsigned short*)alloc((size_t)N_NODES * HID * 2);
    float*  hs     = (float*)alloc((size_t)N_NODES * HID * 4);   // becomes h
    float*  el0    = (float*)alloc((size_t)N_NODES * 2 * 4);
    float*  er0    = (float*)alloc((size_t)N_NODES * 2 * 4);
    float*  el1    = (float*)alloc((size_t)N_NODES * 2 * 4);
    float*  er1    = (float*)alloc((size_t)N_NODES * 2 * 4);
    int*    bincnt = (int*)alloc((size_t)2 * NBINS * NBLK * 4);
    int2*   pairs0 = (int2*)alloc((size_t)N_EDGES * 8);
    int2*   pairs1 = (int2*)alloc((size_t)N_EDGES * 8);
    int*    offs0  = (int*)alloc((size_t)(N_NODES + 1) * 4);
    int*    offs1  = (int*)alloc((size_t)(N_NODES + 1) * 4);
    int4*   rec0   = (int4*)alloc((size_t)N_EDGES * 16);
    int4*   rec1   = (int4*)alloc((size_t)N_EDGES * 16);
    double* psum   = (double*)alloc((size_t)512 * 128 * 8);
    double* psumsq = (double*)alloc((size_t)512 * 128 * 8);
    float*  ss     = (float*)alloc(256 * 4);

    // weights -> bf16 (once; 96 KB, stays L2-resident)
    k_prepw<<<48, 256, 0, stream>>>(fc_w0, fc_w1, skip_w, wbf);

    // CSR binning (independent of GEMM)
    dim3 gbin(NBLK, 2);
    k_bincount<<<gbin, 256, 0, stream>>>(dst0, dst1, bincnt);
    k_binscan<<<2, 1024, 0, stream>>>(bincnt);
    k_binscatter<<<gbin, 256, 0, stream>>>(dst0, dst1, src0, src1, ew0, ew1,
                                           bincnt, pairs0, pairs1);

    // MFMA GEMM (B direct from L2, no per-slice barriers) + dots + hs
    k_gemm_mfma<<<(N_NODES + 63) / 64, 256, 0, stream>>>(
        x, wbf, skip_b, al0, ar0, al1, ar1,
        fb0, fb1, el0, er0, el1, er1, hs);

    // CSR finalize: sorted 16B edge records (needs el)
    dim3 gcsr(NBINS, 2);
    k_csr<<<gcsr, 256, 0, stream>>>(bincnt, pairs0, pairs1, el0, el1,
                                    offs0, offs1, rec0, rec1);

    // gather aggregation, h = hs + relu(bias + msgs) in place
    k_aggregate<<<(N_NODES + 3) / 4, 256, 0, stream>>>(
        offs0, rec0, er0, fb0, offs1, rec1, er1, fb1, bias0, bias1, hs);

    k_bnstats<<<512, 256, 0, stream>>>(hs, psum, psumsq);
    k_bn_finalize<<<1, 128, 0, stream>>>(psum, psumsq, gamma, beta, ss);
    k_classify<<<(N_NODES + 63) / 64, 256, 0, stream>>>(
        hs, ss, clf_w, clf_b, out);
}

// Round 9
// 221.400 us; speedup vs baseline: 1.1714x; 1.1714x over previous
//
#include <hip/hip_runtime.h>
#include <hip/hip_bf16.h>

// Problem constants (match reference)
#define N_NODES 50000
#define N_EDGES 800000
#define HID 128          // HEADS*HEAD_DIM
#define NEG_SLOPE 0.2f
#define BN_EPS 1e-5f

// CSR binning parameters
#define NBLK 256         // blocks over edges
#define BINSZ 512        // nodes per bin (power of 2)
#define BINSH 9
#define NBINS 98         // ceil(N_NODES / BINSZ)

typedef __bf16 v8bf __attribute__((ext_vector_type(8)));
typedef float v4f __attribute__((ext_vector_type(4)));

__device__ __forceinline__ float leaky(float v) {
    return (v > 0.f) ? v : v * NEG_SLOPE;
}
__device__ __forceinline__ unsigned int f2bu(float f) {
    __hip_bfloat16 b = __float2bfloat16(f);
    return (unsigned int)*reinterpret_cast<unsigned short*>(&b);
}
__device__ __forceinline__ unsigned int pack2bf(float lo, float hi) {
    return f2bu(lo) | (f2bu(hi) << 16);
}

// ---------------------------------------------------------------------------
// K_prepw: convert the 3 weight matrices to bf16 once (L2-resident afterwards)
// ---------------------------------------------------------------------------
__global__ __launch_bounds__(256) void k_prepw(const float* __restrict__ w0,
                                               const float* __restrict__ w1,
                                               const float* __restrict__ wsk,
                                               unsigned short* __restrict__ wb) {
    const int WQ = 128 * 128 / 4;         // 4096 quads per matrix
    int q = blockIdx.x * 256 + threadIdx.x;
    if (q >= 3 * WQ) return;
    int mat = q >> 12;
    int rem = q & 4095;
    const float* W = (mat == 0) ? w0 : (mat == 1) ? w1 : wsk;
    float4 v = ((const float4*)W)[rem];
    ushort4 o;
    o.x = (unsigned short)f2bu(v.x);
    o.y = (unsigned short)f2bu(v.y);
    o.z = (unsigned short)f2bu(v.z);
    o.w = (unsigned short)f2bu(v.w);
    *(ushort4*)(wb + (size_t)mat * 16384 + rem * 4) = o;
}

// ---------------------------------------------------------------------------
// CSR pass A: per-block LDS histogram of dst bins. grid: (NBLK, 2)
// ---------------------------------------------------------------------------
__global__ __launch_bounds__(256) void k_bincount(const int* __restrict__ dst0,
                                                  const int* __restrict__ dst1,
                                                  int* __restrict__ bincnt) {
    int rel = blockIdx.y;
    const int* dst = rel ? dst1 : dst0;
    __shared__ int cnt[NBINS];
    for (int i = threadIdx.x; i < NBINS; i += 256) cnt[i] = 0;
    __syncthreads();
    const int CH = (N_EDGES + NBLK - 1) / NBLK;   // 3125
    int b0 = blockIdx.x * CH;
    int b1 = min(N_EDGES, b0 + CH);
    for (int e = b0 + threadIdx.x; e < b1; e += 256)
        atomicAdd(&cnt[dst[e] >> BINSH], 1);
    __syncthreads();
    for (int i = threadIdx.x; i < NBINS; i += 256)
        bincnt[rel * NBINS * NBLK + i * NBLK + blockIdx.x] = cnt[i];
}

// ---------------------------------------------------------------------------
// CSR pass B: in-place exclusive scan of bincnt per relation. grid: (2)
// ---------------------------------------------------------------------------
__global__ __launch_bounds__(1024) void k_binscan(int* __restrict__ bincnt) {
    int* a = bincnt + blockIdx.x * NBINS * NBLK;
    const int TOT = NBINS * NBLK;                 // 25088
    const int CH = (TOT + 1023) / 1024;           // 25
    int tid = threadIdx.x;
    int base = tid * CH;
    int lv[CH];
    int sum = 0;
    for (int i = 0; i < CH; i++) {
        int idx = base + i;
        int v = (idx < TOT) ? a[idx] : 0;
        lv[i] = sum;
        sum += v;
    }
    __shared__ int ls[1024];
    ls[tid] = sum;
    __syncthreads();
    for (int ofs = 1; ofs < 1024; ofs <<= 1) {
        int v = (tid >= ofs) ? ls[tid - ofs] : 0;
        __syncthreads();
        ls[tid] += v;
        __syncthreads();
    }
    int pre = tid ? ls[tid - 1] : 0;
    for (int i = 0; i < CH; i++) {
        int idx = base + i;
        if (idx < TOT) a[idx] = pre + lv[i];
    }
}

// ---------------------------------------------------------------------------
// CSR pass C: scatter packed (dst_local|src<<9, ew) 8B pairs into
// per-(bin,block) contiguous runs. grid: (NBLK, 2)
// ---------------------------------------------------------------------------
__global__ __launch_bounds__(256) void k_binscatter(const int* __restrict__ dst0,
                                                    const int* __restrict__ dst1,
                                                    const int* __restrict__ src0,
                                                    const int* __restrict__ src1,
                                                    const float* __restrict__ ew0,
                                                    const float* __restrict__ ew1,
                                                    const int* __restrict__ bincnt,
                                                    int2* __restrict__ pairs0,
                                                    int2* __restrict__ pairs1) {
    int rel = blockIdx.y;
    const int* dst = rel ? dst1 : dst0;
    const int* src = rel ? src1 : src0;
    const float* ew = rel ? ew1 : ew0;
    int2* pairs = rel ? pairs1 : pairs0;
    __shared__ int cur[NBINS];
    for (int i = threadIdx.x; i < NBINS; i += 256)
        cur[i] = bincnt[rel * NBINS * NBLK + i * NBLK + blockIdx.x];
    __syncthreads();
    const int CH = (N_EDGES + NBLK - 1) / NBLK;
    int b0 = blockIdx.x * CH;
    int b1 = min(N_EDGES, b0 + CH);
    for (int e = b0 + threadIdx.x; e < b1; e += 256) {
        int d = dst[e];
        int pos = atomicAdd(&cur[d >> BINSH], 1);
        unsigned int packed = (unsigned int)(d & (BINSZ - 1)) |
                              ((unsigned int)src[e] << BINSH);
        pairs[pos] = make_int2((int)packed, __float_as_int(ew[e]));
    }
}

// ---------------------------------------------------------------------------
// CSR pass D: per (rel,bin): LDS histogram -> scan -> offs (+sentinel) ->
// place 16B edge records (srcByteOff, ew, el0, el1) sorted by dst.
// grid: (NBINS, 2). Only el is a random gather (8B/edge).
// ---------------------------------------------------------------------------
__global__ __launch_bounds__(256) void k_csr(const int* __restrict__ bincnt,
                                             const int2* __restrict__ pairs0,
                                             const int2* __restrict__ pairs1,
                                             const float* __restrict__ el0,
                                             const float* __restrict__ el1,
                                             int* __restrict__ offs0,
                                             int* __restrict__ offs1,
                                             int4* __restrict__ rec0,
                                             int4* __restrict__ rec1) {
    int rel = blockIdx.y;
    const int2* pairs = rel ? pairs1 : pairs0;
    const float* el = rel ? el1 : el0;
    int* offs = rel ? offs1 : offs0;
    int4* rec = rel ? rec1 : rec0;
    int bin = blockIdx.x;
    int tid = threadIdx.x;
    const int* bc = bincnt + rel * NBINS * NBLK;
    int pbase = bc[bin * NBLK];
    int pend = (bin < NBINS - 1) ? bc[(bin + 1) * NBLK] : N_EDGES;
    int n0 = bin << BINSH;
    int nn = min(N_NODES - n0, BINSZ);

    __shared__ int s_deg[BINSZ];
    __shared__ int s_ts[256];
    for (int i = tid; i < BINSZ; i += 256) s_deg[i] = 0;
    __syncthreads();
    for (int p = pbase + tid; p < pend; p += 256)
        atomicAdd(&s_deg[((unsigned int)pairs[p].x) & (BINSZ - 1)], 1);
    __syncthreads();

    int d0 = s_deg[tid * 2], d1 = s_deg[tid * 2 + 1];
    s_ts[tid] = d0 + d1;
    __syncthreads();
    for (int ofs = 1; ofs < 256; ofs <<= 1) {
        int v = (tid >= ofs) ? s_ts[tid - ofs] : 0;
        __syncthreads();
        s_ts[tid] += v;
        __syncthreads();
    }
    int pre = tid ? s_ts[tid - 1] : 0;
    s_deg[tid * 2] = pbase + pre;
    s_deg[tid * 2 + 1] = pbase + pre + d0;
    __syncthreads();

    for (int l = tid; l < nn; l += 256) offs[n0 + l] = s_deg[l];
    if (bin == NBINS - 1 && tid == 0) offs[N_NODES] = N_EDGES;
    __syncthreads();

    for (int p = pbase + tid; p < pend; p += 256) {
        int2 pr = pairs[p];
        unsigned int u = (unsigned int)pr.x;
        int dl = (int)(u & (BINSZ - 1));
        int s = (int)(u >> BINSH);
        int pos = atomicAdd(&s_deg[dl], 1);
        float2 ev = *(const float2*)(el + 2 * s);
        // store src as BYTE offset into fb (s * HID * 2 = s*256)
        rec[pos] = make_int4(s << 8, pr.y,
                             __float_as_int(ev.x), __float_as_int(ev.y));
    }
}

// ---------------------------------------------------------------------------
// K1: MFMA GEMM, merged: block = 64 rows, loops over all 6 (mat,half) slices.
// A staged once (f32->bf16 inline, XOR-swizzled); B staged per slice from
// pre-converted bf16 weights (no conversion, half traffic).
// grid (782). Block = 4 waves; wave = 16 rows x 64 cols per slice.
// ---------------------------------------------------------------------------
__global__ __launch_bounds__(256) void k_gemm_mfma(
    const float* __restrict__ x, const unsigned short* __restrict__ wb,
    const float* __restrict__ skip_b,
    const float* __restrict__ al0, const float* __restrict__ ar0,
    const float* __restrict__ al1, const float* __restrict__ ar1,
    unsigned short* __restrict__ fb0, unsigned short* __restrict__ fb1,
    float* __restrict__ el0, float* __restrict__ er0,
    float* __restrict__ el1, float* __restrict__ er1,
    float* __restrict__ hs) {
    __shared__ unsigned short As[64][128];
    __shared__ unsigned short Bs[64][128];
    int tid = threadIdx.x;
    int m0 = blockIdx.x * 64;

    // stage A once from f32, convert, XOR-swizzle on 16B granules
#pragma unroll
    for (int i = 0; i < 4; i++) {
        int idx = tid * 4 + i;
        int row = idx >> 4, seg = idx & 15;
        int gr = m0 + row;
        uint4 o = make_uint4(0, 0, 0, 0);
        if (gr < N_NODES) {
            const float* p = x + (size_t)gr * HID + seg * 8;
            float4 p0 = *(const float4*)p;
            float4 p1 = *(const float4*)(p + 4);
            o.x = pack2bf(p0.x, p0.y);
            o.y = pack2bf(p0.z, p0.w);
            o.z = pack2bf(p1.x, p1.y);
            o.w = pack2bf(p1.z, p1.w);
        }
        *(uint4*)(&As[row][(seg ^ (row & 7)) * 8]) = o;
    }
    __syncthreads();

    int w = tid >> 6, l = tid & 63;
    int lr = l & 15, lg = l >> 4;
    int arow = w * 16 + lr;
    v8bf afrag[4];
#pragma unroll
    for (int kb = 0; kb < 4; kb++)
        afrag[kb] = *(v8bf*)(&As[arow][((kb * 4 + lg) ^ (arow & 7)) * 8]);

    for (int s = 0; s < 6; s++) {
        int mat = s >> 1;                 // 0=fc_w0, 1=fc_w1, 2=skip_w
        int j0 = (s & 1) * 64;
        const unsigned short* wmat = wb + (size_t)mat * 16384 + j0 * HID;
        __syncthreads();                  // prior slice's Bs reads complete
#pragma unroll
        for (int i = 0; i < 4; i++) {
            int idx = tid * 4 + i;
            int row = idx >> 4, seg = idx & 15;
            uint4 wv = *(const uint4*)(wmat + row * HID + seg * 8);
            *(uint4*)(&Bs[row][(seg ^ (row & 7)) * 8]) = wv;
        }
        __syncthreads();

        v4f acc[4] = {};
#pragma unroll
        for (int nt = 0; nt < 4; nt++) {
            int brow = nt * 16 + lr;
#pragma unroll
            for (int kb = 0; kb < 4; kb++) {
                v8bf bfrag =
                    *(v8bf*)(&Bs[brow][((kb * 4 + lg) ^ (brow & 7)) * 8]);
                acc[nt] = __builtin_amdgcn_mfma_f32_16x16x32_bf16(
                    afrag[kb], bfrag, acc[nt], 0, 0, 0);
            }
        }

        // C/D layout: col = lane&15, row = (lane>>4)*4 + r   [m89-verified]
        if (mat < 2) {
            int h = s & 1;
            const float* al = mat ? al1 : al0;
            const float* ar = mat ? ar1 : ar0;
            float* elp = mat ? el1 : el0;
            float* erp = mat ? er1 : er0;
            unsigned short* fbp = mat ? fb1 : fb0;
            float elv[4] = {0.f, 0.f, 0.f, 0.f};
            float erv[4] = {0.f, 0.f, 0.f, 0.f};
#pragma unroll
            for (int nt = 0; nt < 4; nt++) {
                int colg = j0 + nt * 16 + lr;
                float av = al[colg], rv = ar[colg];
#pragma unroll
                for (int r = 0; r < 4; r++) {
                    elv[r] += acc[nt][r] * av;
                    erv[r] += acc[nt][r] * rv;
                }
            }
#pragma unroll
            for (int m = 1; m < 16; m <<= 1)
#pragma unroll
                for (int r = 0; r < 4; r++) {
                    elv[r] += __shfl_xor(elv[r], m);
                    erv[r] += __shfl_xor(erv[r], m);
                }
#pragma unroll
            for (int r = 0; r < 4; r++) {
                int grow = m0 + w * 16 + lg * 4 + r;
                if (grow >= N_NODES) continue;
#pragma unroll
                for (int nt = 0; nt < 4; nt++) {
                    int colg = j0 + nt * 16 + lr;
                    fbp[(size_t)grow * HID + colg] =
                        (unsigned short)f2bu(acc[nt][r]);
                }
                if (lr == 0) {
                    elp[grow * 2 + h] = elv[r];
                    erp[grow * 2 + h] = erv[r];
                }
            }
        } else {
#pragma unroll
            for (int r = 0; r < 4; r++) {
                int grow = m0 + w * 16 + lg * 4 + r;
                if (grow >= N_NODES) continue;
#pragma unroll
                for (int nt = 0; nt < 4; nt++) {
                    int colg = j0 + nt * 16 + lr;
                    hs[(size_t)grow * HID + colg] = acc[nt][r] + skip_b[colg];
                }
            }
        }
    }
}

// ---------------------------------------------------------------------------
// K_aggregate: wave per dst node. Sequential 16B edge records; alpha packed
// as bf16x2; src pre-multiplied to byte offset (no 64-bit mul in inner loop).
// Inner loop: 2 shfl + 1 select + 1 uint4 load + 16 unpack-FMA. h in place.
// ---------------------------------------------------------------------------
__device__ __forceinline__ void agg_rel2(const int* __restrict__ offs,
                                         const int4* __restrict__ rec,
                                         const float* __restrict__ er,
                                         const unsigned char* __restrict__ fbb,
                                         int n, int lane, int sub,
                                         int hh, float* a) {
    int b = offs[n];
    int e_end = offs[n + 1];
    int deg = e_end - b;
    if (deg <= 0) return;
    float ern0 = er[2 * n], ern1 = er[2 * n + 1];

    const int NC = 4;
    int cs[NC];
    float cw0[NC], cw1[NC];
    unsigned int cpk[NC];
    float d0 = 0.f, d1 = 0.f;
    int nchunk = (deg + 63) >> 6;
    for (int ch = 0; ch < nchunk; ch++) {
        int p = b + (ch << 6) + lane;
        int s = 0;
        float w0 = 0.f, w1 = 0.f;
        if (p < e_end) {
            int4 r = rec[p];
            s = r.x;
            float wgt = __int_as_float(r.y);
            float x0 = expf(leaky(__int_as_float(r.z) + ern0));
            float x1 = expf(leaky(__int_as_float(r.w) + ern1));
            d0 += x0;
            d1 += x1;
            w0 = x0 * wgt;
            w1 = x1 * wgt;
        }
        if (ch < NC) {
            cs[ch] = s;
            cw0[ch] = w0;
            cw1[ch] = w1;
        }
    }
#pragma unroll
    for (int m = 32; m; m >>= 1) {
        d0 += __shfl_xor(d0, m);
        d1 += __shfl_xor(d1, m);
    }
    float inv0 = 1.f / d0, inv1 = 1.f / d1;
#pragma unroll
    for (int ch = 0; ch < NC; ch++)
        cpk[ch] = pack2bf(cw0[ch] * inv0, cw1[ch] * inv1);

    for (int ch = 0; ch < nchunk; ch++) {
        int s;
        unsigned int pk;
        if (ch < NC) {
            s = cs[ch];
            pk = cpk[ch];
        } else {
            int p = b + (ch << 6) + lane;
            s = 0;
            pk = 0;
            if (p < e_end) {
                int4 r = rec[p];
                s = r.x;
                float wgt = __int_as_float(r.y);
                float w0 = expf(leaky(__int_as_float(r.z) + ern0)) * wgt;
                float w1 = expf(leaky(__int_as_float(r.w) + ern1)) * wgt;
                pk = pack2bf(w0 * inv0, w1 * inv1);
            }
        }
        int cnt = deg - (ch << 6);
        if (cnt > 64) cnt = 64;
        int ng = (cnt + 3) >> 2;
#pragma unroll 2
        for (int g = 0; g < ng; g++) {
            int sl = (g << 2) + sub;
            int sj = __shfl(s, sl);                      // byte offset
            unsigned int pkj = (unsigned int)__shfl((int)pk, sl);
            float aj = __uint_as_float(hh ? (pkj & 0xffff0000u) : (pkj << 16));
            uint4 fv = *(const uint4*)(fbb + sj);
            a[0] += aj * __uint_as_float(fv.x << 16);
            a[1] += aj * __uint_as_float(fv.x & 0xffff0000u);
            a[2] += aj * __uint_as_float(fv.y << 16);
            a[3] += aj * __uint_as_float(fv.y & 0xffff0000u);
            a[4] += aj * __uint_as_float(fv.z << 16);
            a[5] += aj * __uint_as_float(fv.z & 0xffff0000u);
            a[6] += aj * __uint_as_float(fv.w << 16);
            a[7] += aj * __uint_as_float(fv.w & 0xffff0000u);
        }
    }
}

__global__ __launch_bounds__(256) void k_aggregate(
    const int* __restrict__ offs0, const int4* __restrict__ rec0,
    const float* __restrict__ er0, const unsigned short* __restrict__ fb0,
    const int* __restrict__ offs1, const int4* __restrict__ rec1,
    const float* __restrict__ er1, const unsigned short* __restrict__ fb1,
    const float* __restrict__ bias0, const float* __restrict__ bias1,
    float* __restrict__ h) {
    int wave = threadIdx.x >> 6, lane = threadIdx.x & 63;
    int n = blockIdx.x * 4 + wave;
    if (n >= N_NODES) return;
    int cb = lane & 15;        // col block: cols cb*8 .. cb*8+7
    int sub = lane >> 4;       // sub-edge slot
    int hh = cb >> 3;          // head of these cols
    float a[8] = {0.f, 0.f, 0.f, 0.f, 0.f, 0.f, 0.f, 0.f};
    const unsigned char* fbb0 = (const unsigned char*)fb0 + cb * 16;
    const unsigned char* fbb1 = (const unsigned char*)fb1 + cb * 16;
    agg_rel2(offs0, rec0, er0, fbb0, n, lane, sub, hh, a);
    agg_rel2(offs1, rec1, er1, fbb1, n, lane, sub, hh, a);
#pragma unroll
    for (int j = 0; j < 8; j++) {
        a[j] += __shfl_xor(a[j], 16);
        a[j] += __shfl_xor(a[j], 32);
    }
    if (sub == 0) {
        size_t base = (size_t)n * HID + cb * 8;
        float4 v0 = *(const float4*)(h + base);
        float4 v1 = *(const float4*)(h + base + 4);
        int c0 = cb * 8;
        float4 o0, o1;
        o0.x = v0.x + fmaxf(a[0] + bias0[c0 + 0] + bias1[c0 + 0], 0.f);
        o0.y = v0.y + fmaxf(a[1] + bias0[c0 + 1] + bias1[c0 + 1], 0.f);
        o0.z = v0.z + fmaxf(a[2] + bias0[c0 + 2] + bias1[c0 + 2], 0.f);
        o0.w = v0.w + fmaxf(a[3] + bias0[c0 + 3] + bias1[c0 + 3], 0.f);
        o1.x = v1.x + fmaxf(a[4] + bias0[c0 + 4] + bias1[c0 + 4], 0.f);
        o1.y = v1.y + fmaxf(a[5] + bias0[c0 + 5] + bias1[c0 + 5], 0.f);
        o1.z = v1.z + fmaxf(a[6] + bias0[c0 + 6] + bias1[c0 + 6], 0.f);
        o1.w = v1.w + fmaxf(a[7] + bias0[c0 + 7] + bias1[c0 + 7], 0.f);
        *(float4*)(h + base) = o0;
        *(float4*)(h + base + 4) = o1;
    }
}

// ---------------------------------------------------------------------------
// K_bnstats: per-column partial sums over h (float4 loads).
// EXACTLY 512 blocks x 256 threads.
// ---------------------------------------------------------------------------
__global__ __launch_bounds__(256) void k_bnstats(const float* __restrict__ h,
                                                 double* __restrict__ psum,
                                                 double* __restrict__ psumsq) {
    int tid = threadIdx.x;
    const float4* h4 = (const float4*)h;
    double s[4] = {0.0, 0.0, 0.0, 0.0};
    double q[4] = {0.0, 0.0, 0.0, 0.0};
    const int totalv = N_NODES * HID / 4;         // 1.6M float4s
    const int stride = 512 * 256;                 // multiple of 32: cols fixed
    for (int i = blockIdx.x * 256 + tid; i < totalv; i += stride) {
        float4 v = h4[i];
        s[0] += v.x; q[0] += (double)v.x * v.x;
        s[1] += v.y; q[1] += (double)v.y * v.y;
        s[2] += v.z; q[2] += (double)v.z * v.z;
        s[3] += v.w; q[3] += (double)v.w * v.w;
    }
    __shared__ double ls[256][4], lq[256][4];
#pragma unroll
    for (int j = 0; j < 4; j++) {
        ls[tid][j] = s[j];
        lq[tid][j] = q[j];
    }
    __syncthreads();
    if (tid < 32) {                                // col quad = tid*4 + j
#pragma unroll
        for (int j = 0; j < 4; j++) {
            double ss = 0.0, qq = 0.0;
            for (int t = tid; t < 256; t += 32) {
                ss += ls[t][j];
                qq += lq[t][j];
            }
            psum[blockIdx.x * 128 + tid * 4 + j] = ss;
            psumsq[blockIdx.x * 128 + tid * 4 + j] = qq;
        }
    }
}

__global__ void k_bn_finalize(const double* __restrict__ psum,
                              const double* __restrict__ psumsq,
                              const float* __restrict__ gamma,
                              const float* __restrict__ beta,
                              float* __restrict__ ss) {
    int c = threadIdx.x;
    double s = 0.0, q = 0.0;
    for (int b = 0; b < 512; b++) {
        s += psum[b * 128 + c];
        q += psumsq[b * 128 + c];
    }
    double mu = s / N_NODES;
    double var = q / N_NODES - mu * mu;
    float sc = gamma[c] * (float)(1.0 / sqrt(var + (double)BN_EPS));
    ss[c] = sc;
    ss[128 + c] = beta[c] - (float)mu * sc;
}

// ---------------------------------------------------------------------------
// K_classify: MFMA 16x16x32. Wave = 16 nodes x 16 classes, K=128.
// A = relu(h*sc+sh) -> bf16; B = clf_w -> bf16. grid 782 x 4 waves.
// ---------------------------------------------------------------------------
__global__ __launch_bounds__(256) void k_classify(const float* __restrict__ h,
                                                  const float* __restrict__ ss,
                                                  const float* __restrict__ clf_w,
                                                  const float* __restrict__ clf_b,
                                                  float* __restrict__ out) {
    int w = threadIdx.x >> 6, l = threadIdx.x & 63;
    int lr = l & 15, lg = l >> 4;
    int n0 = (blockIdx.x * 4 + w) * 16;
    if (n0 >= N_NODES) return;

    v8bf afrag[4], bfrag[4];
#pragma unroll
    for (int kb = 0; kb < 4; kb++) {
        int k0 = kb * 32 + lg * 8;
        const float* bp = clf_w + lr * HID + k0;
        float4 b0 = *(const float4*)bp;
        float4 b1 = *(const float4*)(bp + 4);
        bfrag[kb][0] = (__bf16)b0.x; bfrag[kb][1] = (__bf16)b0.y;
        bfrag[kb][2] = (__bf16)b0.z; bfrag[kb][3] = (__bf16)b0.w;
        bfrag[kb][4] = (__bf16)b1.x; bfrag[kb][5] = (__bf16)b1.y;
        bfrag[kb][6] = (__bf16)b1.z; bfrag[kb][7] = (__bf16)b1.w;
        const float* ap = h + (size_t)(n0 + lr) * HID + k0;
        float4 a0 = *(const float4*)ap;
        float4 a1 = *(const float4*)(ap + 4);
        float4 sc0 = *(const float4*)(ss + k0);
        float4 sc1 = *(const float4*)(ss + k0 + 4);
        float4 sh0 = *(const float4*)(ss + 128 + k0);
        float4 sh1 = *(const float4*)(ss + 128 + k0 + 4);
        afrag[kb][0] = (__bf16)fmaxf(a0.x * sc0.x + sh0.x, 0.f);
        afrag[kb][1] = (__bf16)fmaxf(a0.y * sc0.y + sh0.y, 0.f);
        afrag[kb][2] = (__bf16)fmaxf(a0.z * sc0.z + sh0.z, 0.f);
        afrag[kb][3] = (__bf16)fmaxf(a0.w * sc0.w + sh0.w, 0.f);
        afrag[kb][4] = (__bf16)fmaxf(a1.x * sc1.x + sh1.x, 0.f);
        afrag[kb][5] = (__bf16)fmaxf(a1.y * sc1.y + sh1.y, 0.f);
        afrag[kb][6] = (__bf16)fmaxf(a1.z * sc1.z + sh1.z, 0.f);
        afrag[kb][7] = (__bf16)fmaxf(a1.w * sc1.w + sh1.w, 0.f);
    }
    v4f acc = {};
#pragma unroll
    for (int kb = 0; kb < 4; kb++)
        acc = __builtin_amdgcn_mfma_f32_16x16x32_bf16(afrag[kb], bfrag[kb],
                                                      acc, 0, 0, 0);
    float cb = clf_b[lr];
#pragma unroll
    for (int r = 0; r < 4; r++) {
        int n = n0 + lg * 4 + r;
        out[(size_t)n * 16 + lr] = acc[r] + cb;
    }
}

// ---------------------------------------------------------------------------
extern "C" void kernel_launch(void* const* d_in, const int* in_sizes, int n_in,
                              void* d_out, int out_size, void* d_ws, size_t ws_size,
                              hipStream_t stream) {
    (void)in_sizes; (void)n_in; (void)out_size; (void)ws_size;
    const float* x      = (const float*)d_in[0];
    const int*   src0   = (const int*)d_in[1];
    const int*   dst0   = (const int*)d_in[2];
    const float* ew0    = (const float*)d_in[3];
    const int*   src1   = (const int*)d_in[4];
    const int*   dst1   = (const int*)d_in[5];
    const float* ew1    = (const float*)d_in[6];
    const float* fc_w0  = (const float*)d_in[7];
    const float* bias0  = (const float*)d_in[8];
    const float* al0    = (const float*)d_in[9];
    const float* ar0    = (const float*)d_in[10];
    const float* fc_w1  = (const float*)d_in[11];
    const float* bias1  = (const float*)d_in[12];
    const float* al1    = (const float*)d_in[13];
    const float* ar1    = (const float*)d_in[14];
    const float* skip_w = (const float*)d_in[15];
    const float* skip_b = (const float*)d_in[16];
    const float* gamma  = (const float*)d_in[17];
    const float* beta   = (const float*)d_in[18];
    const float* clf_w  = (const float*)d_in[19];
    const float* clf_b  = (const float*)d_in[20];
    float* out = (float*)d_out;

    char* wsp = (char*)d_ws;
    size_t off = 0;
    auto alloc = [&](size_t bytes) -> char* {
        char* p = wsp + off;
        off += (bytes + 255) & ~(size_t)255;
        return p;
    };
    unsigned short* wbf = (unsigned short*)alloc((size_t)3 * 16384 * 2);
    unsigned short* fb0 = (unsigned short*)alloc((size_t)N_NODES * HID * 2);
    unsigned short* fb1 = (unsigned short*)alloc((size_t)N_NODES * HID * 2);
    float*  hs     = (float*)alloc((size_t)N_NODES * HID * 4);   // becomes h
    float*  el0    = (float*)alloc((size_t)N_NODES * 2 * 4);
    float*  er0    = (float*)alloc((size_t)N_NODES * 2 * 4);
    float*  el1    = (float*)alloc((size_t)N_NODES * 2 * 4);
    float*  er1    = (float*)alloc((size_t)N_NODES * 2 * 4);
    int*    bincnt = (int*)alloc((size_t)2 * NBINS * NBLK * 4);
    int2*   pairs0 = (int2*)alloc((size_t)N_EDGES * 8);
    int2*   pairs1 = (int2*)alloc((size_t)N_EDGES * 8);
    int*    offs0  = (int*)alloc((size_t)(N_NODES + 1) * 4);
    int*    offs1  = (int*)alloc((size_t)(N_NODES + 1) * 4);
    int4*   rec0   = (int4*)alloc((size_t)N_EDGES * 16);
    int4*   rec1   = (int4*)alloc((size_t)N_EDGES * 16);
    double* psum   = (double*)alloc((size_t)512 * 128 * 8);
    double* psumsq = (double*)alloc((size_t)512 * 128 * 8);
    float*  ss     = (float*)alloc(256 * 4);

    // weights -> bf16 (once; 96 KB, stays L2-resident)
    k_prepw<<<48, 256, 0, stream>>>(fc_w0, fc_w1, skip_w, wbf);

    // CSR binning (independent of GEMM)
    dim3 gbin(NBLK, 2);
    k_bincount<<<gbin, 256, 0, stream>>>(dst0, dst1, bincnt);
    k_binscan<<<2, 1024, 0, stream>>>(bincnt);
    k_binscatter<<<gbin, 256, 0, stream>>>(dst0, dst1, src0, src1, ew0, ew1,
                                           bincnt, pairs0, pairs1);

    // MFMA GEMM (bf16 B staged in LDS) + attention dots + hs
    k_gemm_mfma<<<(N_NODES + 63) / 64, 256, 0, stream>>>(
        x, wbf, skip_b, al0, ar0, al1, ar1,
        fb0, fb1, el0, er0, el1, er1, hs);

    // CSR finalize: sorted 16B edge records (needs el)
    dim3 gcsr(NBINS, 2);
    k_csr<<<gcsr, 256, 0, stream>>>(bincnt, pairs0, pairs1, el0, el1,
                                    offs0, offs1, rec0, rec1);

    // gather aggregation, h = hs + relu(bias + msgs) in place
    k_aggregate<<<(N_NODES + 3) / 4, 256, 0, stream>>>(
        offs0, rec0, er0, fb0, offs1, rec1, er1, fb1, bias0, bias1, hs);

    k_bnstats<<<512, 256, 0, stream>>>(hs, psum, psumsq);
    k_bn_finalize<<<1, 128, 0, stream>>>(psum, psumsq, gamma, beta, ss);
    k_classify<<<(N_NODES + 63) / 64, 256, 0, stream>>>(
        hs, ss, clf_w, clf_b, out);
}